// Round 15
// baseline (196.749 us; speedup 1.0000x reference)
//
#include <hip/hip_runtime.h>
#include <hip/hip_bf16.h>
#include <stdint.h>

// B=2, T=2048, E=1024, H=16, D=64 ; M = B*T = 4096
// Inputs fp32, output fp32. bf16 MFMA 16x16x32, fp32 accumulate.
// R29 = R28 with attn QBLK 64 -> 128: 512 blocks x 512 threads (8 waves).
// Per-wave inner code identical; K/V tile now shared by 128 q-rows ->
// total K/V fetch and per-thread staging halve; occupancy ceiling 29->50%.
// Wave w's diagonal tile myend = 2*qb0 + (w>>2); waves 0-3 skip compute
// (keep barriers) on the final tile. Balanced qb0 perm: perm(g)+perm(g+8)=15.
// GEMM/prep byte-identical to R28. ws: 24 MB.

typedef __attribute__((ext_vector_type(8))) short short8;    // 8 bf16
typedef __attribute__((ext_vector_type(4))) short short4v;   // 4 bf16
typedef __attribute__((ext_vector_type(4))) float f32x4;

#define MFMA16(a, b, c) __builtin_amdgcn_mfma_f32_16x16x32_bf16((a), (b), (c), 0, 0, 0)

static __device__ __forceinline__ unsigned short f2bf(float f) {
    union { float f; unsigned int u; } v; v.f = f;
    unsigned int r = v.u + 0x7fffu + ((v.u >> 16) & 1u);   // RNE
    return (unsigned short)(r >> 16);
}

static __device__ __forceinline__ float exp2_hw(float x) {
    float r;
    asm("v_exp_f32 %0, %1" : "=v"(r) : "v"(x));    // HW 2^x, full range
    return r;
}

// async global->LDS, 16B per lane; LDS dest is wave-uniform base + lane*16
static __device__ __forceinline__ void gld16(const unsigned short* g,
                                             unsigned short* l) {
    __builtin_amdgcn_global_load_lds(
        (const __attribute__((address_space(1))) unsigned int*)g,
        (__attribute__((address_space(3))) unsigned int*)l, 16, 0, 0);
}

// ---------------- fused prep: x -> bf16 (blocks 0..2047) ;
//                  W [K,N] fp32 -> Wt [N,K] bf16 for 4 weights (blocks 2048..3071)
__global__ __launch_bounds__(256) void k_prep(
        const float* __restrict__ x, unsigned short* __restrict__ xb,
        const float* __restrict__ W0, const float* __restrict__ W1,
        const float* __restrict__ W2, const float* __restrict__ W3,
        unsigned short* __restrict__ T0, unsigned short* __restrict__ T1,
        unsigned short* __restrict__ T2, unsigned short* __restrict__ T3) {
    const int tid = threadIdx.x;
    if (blockIdx.x < 2048) {                       // ---- convert x -> bf16
        int i = blockIdx.x * 256 + tid;            // 8 elements/thread
        const float4* p = (const float4*)(x + (size_t)i * 8);
        float4 a = p[0], b = p[1];
        short8 o;
        o[0] = (short)f2bf(a.x); o[1] = (short)f2bf(a.y);
        o[2] = (short)f2bf(a.z); o[3] = (short)f2bf(a.w);
        o[4] = (short)f2bf(b.x); o[5] = (short)f2bf(b.y);
        o[6] = (short)f2bf(b.z); o[7] = (short)f2bf(b.w);
        ((short8*)xb)[i] = o;
        return;
    }
    // ---- transpose+convert weights
    const int t = blockIdx.x - 2048;               // 1024 blocks: z*256 + y*16 + x
    const int z = t >> 8, by = (t >> 4) & 15, bx = t & 15;
    const float* W = (z == 0) ? W0 : (z == 1) ? W1 : (z == 2) ? W2 : W3;
    unsigned short* Wt = (z == 0) ? T0 : (z == 1) ? T1 : (z == 2) ? T2 : T3;
    __shared__ float tw[64][68];
    const int k0 = bx * 64, n0 = by * 64;
#pragma unroll
    for (int r = 0; r < 4; ++r) {
        int i = tid + r * 256;
        int row = i >> 4, c4 = (i & 15) * 4;
        float4 v = *(const float4*)(W + (size_t)(k0 + row) * 1024 + n0 + c4);
        *(float4*)(&tw[row][c4]) = v;
    }
    __syncthreads();
#pragma unroll
    for (int r = 0; r < 2; ++r) {
        int i = tid + r * 256;
        int nrow = i >> 3, kc = (i & 7) * 8;
        short8 o;
#pragma unroll
        for (int j = 0; j < 8; ++j) o[j] = (short)f2bf(tw[kc + j][nrow]);
        *(short8*)(Wt + (size_t)(n0 + nrow) * 1024 + k0 + kc) = o;
    }
}

// ------------------------ GEMM, 128x64 tile, BK=64 (two k-half sub-tiles)
// C[M=4096, N] = A[M,1024](bf16) @ Bt[N,1024]^T + bias ; 16 K-iters.
// 4 waves as 2x2 -> each wave 64x32 out (acc 4x2, 16 MFMA/iter).
// MODE 0 (QKV, N=3072, grid 32x48): n0<1024 -> Qb (PRE-SCALED by log2e/32) ;
// <2048 -> Kb ; else V transposed into Vt.
// MODE 1 (O, N=1024, grid 32x16): fp32 out + bias.
template <int MODE>
__global__ __launch_bounds__(256) void k_gemm2(const unsigned short* __restrict__ A,
                                               const unsigned short* __restrict__ Bt,
                                               const float* __restrict__ bq,
                                               const float* __restrict__ bk,
                                               const float* __restrict__ bv,
                                               unsigned short* __restrict__ Qb,
                                               unsigned short* __restrict__ Kb,
                                               unsigned short* __restrict__ Vt,
                                               float* __restrict__ Co) {
    __shared__ unsigned short As[2][128 * 32];     // k-half sub-tiles, 8 KB each
    __shared__ unsigned short Bs[2][64 * 32];      // 4 KB each
    const int tid = threadIdx.x;
    const int w = tid >> 6, lane = tid & 63;
    const int quad = lane >> 4, l16 = lane & 15;
    const int wm = w >> 1, wn = w & 1;             // 2x2 waves, 64x32 out each
    const int m0 = blockIdx.x * 128, n0 = blockIdx.y * 64;
    const int lrow = lane >> 2, lch = (lane & 3) * 8;

    const unsigned short* ga = A + (size_t)(m0 + w * 32 + lrow) * 1024 + lch;
    const unsigned short* gb = Bt + (size_t)(n0 + w * 16 + (lane >> 2)) * 1024 + lch;
    const int lofsA = w * 1024 + lane * 8;         // == (w*32+lrow)*32 + lch
    const int lofsB = w * 512 + lane * 8;          // == (w*16+(lane>>2))*32 + lch

    f32x4 acc[4][2];
#pragma unroll
    for (int mt = 0; mt < 4; ++mt)
#pragma unroll
        for (int nt = 0; nt < 2; ++nt) acc[mt][nt] = (f32x4){0.f, 0.f, 0.f, 0.f};

    for (int k0 = 0; k0 < 1024; k0 += 64) {
        __syncthreads();                           // done reading prev tile
        gld16(ga + k0, &As[0][lofsA]);
        gld16(ga + 16 * 1024 + k0, &As[0][lofsA + 512]);
        gld16(ga + k0 + 32, &As[1][lofsA]);
        gld16(ga + 16 * 1024 + k0 + 32, &As[1][lofsA + 512]);
        gld16(gb + k0, &Bs[0][lofsB]);
        gld16(gb + k0 + 32, &Bs[1][lofsB]);
        __syncthreads();                           // vmcnt drain -> tile ready
#pragma unroll
        for (int kk = 0; kk < 2; ++kk) {
            short8 af[4], bf[2];
#pragma unroll
            for (int mt = 0; mt < 4; ++mt)
                af[mt] = *(const short8*)(&As[kk][(wm * 64 + mt * 16 + l16) * 32 + quad * 8]);
#pragma unroll
            for (int nt = 0; nt < 2; ++nt)
                bf[nt] = *(const short8*)(&Bs[kk][(wn * 32 + nt * 16 + l16) * 32 + quad * 8]);
#pragma unroll
            for (int mt = 0; mt < 4; ++mt)
#pragma unroll
                for (int nt = 0; nt < 2; ++nt)
                    acc[mt][nt] = MFMA16(af[mt], bf[nt], acc[mt][nt]);
        }
    }

    // epilogue: C/D layout col=lane&15, row=quad*4+reg
    if (MODE == 1) {
#pragma unroll
        for (int nt = 0; nt < 2; ++nt) {
            int col = n0 + wn * 32 + nt * 16 + l16;
            float bb = bq[col];
#pragma unroll
            for (int mt = 0; mt < 4; ++mt) {
                int row = m0 + wm * 64 + mt * 16 + quad * 4;
#pragma unroll
                for (int r = 0; r < 4; ++r)
                    Co[(size_t)(row + r) * 1024 + col] = acc[mt][nt][r] + bb;
            }
        }
    } else if (n0 < 2048) {                        // Q (pre-scaled) or K: bf16
        unsigned short* C = (n0 < 1024) ? Qb : Kb;
        const float* bias = (n0 < 1024) ? bq : bk;
        // fold 1/sqrt(E) AND log2e into Q: softmax runs in exp2 domain
        const float sc = (n0 < 1024) ? 0.03125f * 1.44269504f : 1.0f;
        int cb = (n0 < 1024) ? n0 : (n0 - 1024);
#pragma unroll
        for (int nt = 0; nt < 2; ++nt) {
            int col = cb + wn * 32 + nt * 16 + l16;
            float bb = bias[col];
#pragma unroll
            for (int mt = 0; mt < 4; ++mt) {
                int row = m0 + wm * 64 + mt * 16 + quad * 4;
#pragma unroll
                for (int r = 0; r < 4; ++r)
                    C[(size_t)(row + r) * 1024 + col] = f2bf((acc[mt][nt][r] + bb) * sc);
            }
        }
    } else {                                       // V: transposed per-head store
#pragma unroll
        for (int nt = 0; nt < 2; ++nt) {
            int vcol = (n0 - 2048) + wn * 32 + nt * 16 + l16;   // h*64+d
            float bb = bv[vcol];
#pragma unroll
            for (int mt = 0; mt < 4; ++mt) {
                int row = m0 + wm * 64 + mt * 16 + quad * 4;    // b*2048+t, t%4==0
                int b = row >> 11, t = row & 2047;
                short4v o;
#pragma unroll
                for (int r = 0; r < 4; ++r) o[r] = (short)f2bf(acc[mt][nt][r] + bb);
                *(short4v*)(&Vt[((size_t)(b * 16 + (vcol >> 6)) * 64 + (vcol & 63))
                                    * 2048 + t]) = o;
            }
        }
    }
}

// ---------------------------------------------------------------- flash attention
// QBLK=128: 512 blocks x 512 threads (8 waves, 16 q-rows each). Per-lane
// softmax in EXP2 DOMAIN (Q pre-scaled log2e/32, exp = inline-asm v_exp_f32),
// tree reductions, defer-max THR=8, SINGLE-buffer LDS K/V staging with early
// reg prefetch (one short8/thread), mask on wave's diagonal tile, manual RNE
// casts. LDS 36.9KB. grid 512: bh=id&31; qb0 = balanced perm of id>>5.
__global__ __launch_bounds__(512) void k_attn(const unsigned short* __restrict__ Qb,
                                              const unsigned short* __restrict__ Kb,
                                              const unsigned short* __restrict__ Vt,
                                              unsigned short* __restrict__ Ob) {
    __shared__ unsigned short Ks[64][72];          // [k16][d], 144B row stride
    __shared__ unsigned short Vs[64][72];          // [d][k]
    __shared__ unsigned short Ps[8][16][72];       // per-wave P^T relayout
    const int tid = threadIdx.x;
    const int w = tid >> 6, lane = tid & 63;
    const int quad = lane >> 4, l16 = lane & 15;
    const int id = blockIdx.x;
    const int bh = id & 31;                        // XCD-friendly low bits
    const int g = id >> 5;                         // 0..15
    const int qb0 = (g < 8) ? 15 - g : g - 8;      // perm(g)+perm(g+8)=15
    const int b = bh >> 4, h = bh & 15;
    const int qg = qb0 * 128 + w * 16 + l16;       // this lane's q row
    const int ntiles = 2 * qb0 + 2;                // staged K-tiles
    const int myend = 2 * qb0 + (w >> 2);          // wave's diagonal tile
    const f32x4 zero4 = {0.f, 0.f, 0.f, 0.f};

    // staging geometry: 512 b128 chunks/tile, one per thread
    const int srow = tid >> 3, sc8 = (tid & 7) * 8;    // srow 0..63
    const unsigned short* kg0 = Kb + (size_t)(b * 2048) * 1024 + h * 64 + sc8;
    const unsigned short* vg0 = Vt + (size_t)(bh * 64 + srow) * 2048 + sc8;

    // Q as B-operand (pre-scaled by log2e/32): [n=q=l16][k=d=quad*8+j]
    short8 qf[2];
    {
        const unsigned short* qp =
            Qb + (size_t)(b * 2048 + qg) * 1024 + h * 64 + quad * 8;
        qf[0] = *(const short8*)(qp);
        qf[1] = *(const short8*)(qp + 32);
    }
    float m_ = -1e30f, l_ = 0.f;                   // per lane (q), dup over quads
    f32x4 o[4];                                    // O^T: q=l16, d=dt*16+quad*4+r
#pragma unroll
    for (int dt = 0; dt < 4; ++dt) o[dt] = zero4;

    // prologue: stage tile 0
    short8 kr0, vr0;
    kr0 = *(const short8*)(kg0 + (size_t)(srow) * 1024);
    vr0 = *(const short8*)(vg0);
    *(short8*)(&Ks[srow][sc8]) = kr0;
    *(short8*)(&Vs[srow][sc8]) = vr0;
    __syncthreads();

    for (int kt = 0; kt < ntiles; ++kt) {
        const bool more = (kt + 1) < ntiles;
        if (more) {                                // issue loads for kt+1 EARLY;
            kr0 = *(const short8*)(kg0 + (size_t)((kt + 1) * 64 + srow) * 1024);
            vr0 = *(const short8*)(vg0 + (kt + 1) * 64);
        }                                          // ...they fly during compute

        if (kt <= myend) {                         // wave-uniform compute guard
            // S^T = K Q^T : A=K[m=k16=l16][d] from LDS, B=Q. C: col=q, row=k16.
            f32x4 s[4];
#pragma unroll
            for (int kkt = 0; kkt < 4; ++kkt) {
                short8 kf0 = *(const short8*)(&Ks[kkt * 16 + l16][quad * 8]);
                short8 kf1 = *(const short8*)(&Ks[kkt * 16 + l16][32 + quad * 8]);
                s[kkt] = MFMA16(kf0, qf[0], zero4);
                s[kkt] = MFMA16(kf1, qf[1], s[kkt]);
            }

            // causal mask only on this wave's diagonal tile (wave-uniform)
            if (kt == myend) {
#pragma unroll
                for (int kkt = 0; kkt < 4; ++kkt) {
                    int kg_ = kt * 64 + kkt * 16 + quad * 4;
#pragma unroll
                    for (int r = 0; r < 4; ++r)
                        if (kg_ + r > qg) s[kkt][r] = -1e30f;
                }
            }
            // per-lane online softmax in exp2 domain; tree reductions
            float mk[4];
#pragma unroll
            for (int kkt = 0; kkt < 4; ++kkt)
                mk[kkt] = fmaxf(fmaxf(s[kkt][0], s[kkt][1]),
                                fmaxf(s[kkt][2], s[kkt][3]));
            float mx = fmaxf(fmaxf(mk[0], mk[1]), fmaxf(mk[2], mk[3]));
            mx = fmaxf(mx, __shfl_xor(mx, 16, 64));    // reduce over quad lanes
            mx = fmaxf(mx, __shfl_xor(mx, 32, 64));
            // T13 defer-max: rescale only when any lane exceeds m_+8 (P <= 2^8)
            if (__any(mx > m_ + 8.0f)) {
                float mnew = fmaxf(m_, mx);
                float al = exp2_hw(m_ - mnew);
                l_ *= al;
#pragma unroll
                for (int dt = 0; dt < 4; ++dt)
#pragma unroll
                    for (int r = 0; r < 4; ++r) o[dt][r] *= al;
                m_ = mnew;
            }
#pragma unroll
            for (int kkt = 0; kkt < 4; ++kkt)
#pragma unroll
                for (int r = 0; r < 4; ++r)
                    s[kkt][r] = exp2_hw(s[kkt][r] - m_);   // 1-instr HW 2^x
            float sk[4];
#pragma unroll
            for (int kkt = 0; kkt < 4; ++kkt)
                sk[kkt] = (s[kkt][0] + s[kkt][1]) + (s[kkt][2] + s[kkt][3]);
            float sum = (sk[0] + sk[1]) + (sk[2] + sk[3]);
            sum += __shfl_xor(sum, 16, 64);
            sum += __shfl_xor(sum, 32, 64);
            l_ += sum;

            // P^T relayout: per lane 4 consecutive k at row q=l16 -> one b64/kkt
#pragma unroll
            for (int kkt = 0; kkt < 4; ++kkt) {
                short4v pk;
#pragma unroll
                for (int r = 0; r < 4; ++r) pk[r] = (short)f2bf(s[kkt][r]);
                *(short4v*)(&Ps[w][l16][kkt * 16 + quad * 4]) = pk;
            }
            __threadfence_block();                 // lgkmcnt drain (per-wave Ps)

            // O^T += V^T P^T : A=V^T[m=d16=l16][k] from LDS, B=P^T[n=q=l16][k]
#pragma unroll
            for (int kks = 0; kks < 2; ++kks) {
                short8 pf = *(const short8*)(&Ps[w][l16][kks * 32 + quad * 8]);
#pragma unroll
                for (int dt = 0; dt < 4; ++dt) {
                    short8 vf = *(const short8*)(
                        &Vs[dt * 16 + l16][kks * 32 + quad * 8]);
                    o[dt] = MFMA16(vf, pf, o[dt]);
                }
            }
        }

        if (more) {                                // write-late: single buffer
            __syncthreads();                       // all waves done reading K/V
            *(short8*)(&Ks[srow][sc8]) = kr0;
            *(short8*)(&Vs[srow][sc8]) = vr0;
            __syncthreads();                       // tile kt+1 staged
        }
    }

    // epilogue: lane q=qg, d = dt*16+quad*4+r -> 4 consecutive d per b64 store
    float inv = 1.0f / l_;
    unsigned short* op = Ob + (size_t)(b * 2048 + qg) * 1024 + h * 64 + quad * 4;
#pragma unroll
    for (int dt = 0; dt < 4; ++dt) {
        short4v ov;
#pragma unroll
        for (int r = 0; r < 4; ++r) ov[r] = (short)f2bf(o[dt][r] * inv);
        *(short4v*)(op + dt * 16) = ov;
    }
}

// ---------------------------------------------------------------- launch
extern "C" void kernel_launch(void* const* d_in, const int* in_sizes, int n_in,
                              void* d_out, int out_size, void* d_ws, size_t ws_size,
                              hipStream_t stream) {
    const float* x  = (const float*)d_in[0];
    const float* Wq = (const float*)d_in[1];
    const float* bq = (const float*)d_in[2];
    const float* Wk = (const float*)d_in[3];
    const float* bk = (const float*)d_in[4];
    const float* Wv = (const float*)d_in[5];
    const float* bv = (const float*)d_in[6];
    const float* Wo = (const float*)d_in[7];
    const float* bo = (const float*)d_in[8];
    float* out = (float*)d_out;                    // fp32 output

    const size_t M4 = 4194304, M1 = 1048576;
    const size_t NEED = (M4 + M4 + 3 * M1 + M1) * 2;   // 24 MB
    if (ws_size < NEED) return;
    unsigned short* ws = (unsigned short*)d_ws;
    unsigned short* xb  = ws;                      // 8 MB (dead after QKV gemm)
    unsigned short* Ob  = ws;                      //   ... then Ob (attn output)
    unsigned short* Vt  = ws + M4;                 // 8 MB, [(b*16+h)*64+d][t]
    unsigned short* WtQ = ws + 2 * M4;             // 6 MB: Wq^T,Wk^T,Wv^T stacked
    unsigned short* Wto = WtQ + 3 * M1;            // 2 MB: Wo^T
    unsigned short* Qb  = (unsigned short*)d_out;  // 8 MB scratch in d_out
    unsigned short* Kb  = Qb + M4;                 // 8 MB scratch in d_out

    k_prep<<<3072, 256, 0, stream>>>(x, xb, Wq, Wk, Wv, Wo,
                                     WtQ, WtQ + M1, WtQ + 2 * M1, Wto);
    k_gemm2<0><<<dim3(32, 48), 256, 0, stream>>>(xb, WtQ, bq, bk, bv,
                                                 Qb, Kb, Vt, nullptr);
    k_attn<<<512, 512, 0, stream>>>(Qb, Kb, Vt, Ob);
    k_gemm2<1><<<dim3(32, 16), 256, 0, stream>>>(Ob, Wto, bo, nullptr, nullptr,
                                                 nullptr, nullptr, nullptr, out);
}

// Round 16
// 180.626 us; speedup vs baseline: 1.0893x; 1.0893x over previous
//
#include <hip/hip_runtime.h>
#include <hip/hip_bf16.h>
#include <stdint.h>

// B=2, T=2048, E=1024, H=16, D=64 ; M = B*T = 4096
// Inputs fp32, output fp32. bf16 MFMA 16x16x32, fp32 accumulate.
// R30 = R28 (best, 184.7us; R29's QBLK=128 reverted -- 8-wave barriers +
// halved cross-block overlap regressed attn 45.6->57.4) + ONE change:
// attn P-pack and O-store use v_cvt_pk_bf16_f32 (2 floats -> 1 packed dword,
// 1 instr, RNE; T12 recipe) instead of 16x manual 3-op RNE (~-40 VALU/tile).
// GEMM/prep byte-identical to R28. ws: 24 MB.

typedef __attribute__((ext_vector_type(8))) short short8;    // 8 bf16
typedef __attribute__((ext_vector_type(4))) short short4v;   // 4 bf16
typedef __attribute__((ext_vector_type(4))) float f32x4;

#define MFMA16(a, b, c) __builtin_amdgcn_mfma_f32_16x16x32_bf16((a), (b), (c), 0, 0, 0)

static __device__ __forceinline__ unsigned short f2bf(float f) {
    union { float f; unsigned int u; } v; v.f = f;
    unsigned int r = v.u + 0x7fffu + ((v.u >> 16) & 1u);   // RNE
    return (unsigned short)(r >> 16);
}

static __device__ __forceinline__ float exp2_hw(float x) {
    float r;
    asm("v_exp_f32 %0, %1" : "=v"(r) : "v"(x));    // HW 2^x, full range
    return r;
}

static __device__ __forceinline__ unsigned int cvtpk_bf16(float lo, float hi) {
    unsigned int r;                                // r.lo16=bf16(lo), r.hi16=bf16(hi)
    asm("v_cvt_pk_bf16_f32 %0, %1, %2" : "=v"(r) : "v"(lo), "v"(hi));
    return r;
}

// async global->LDS, 16B per lane; LDS dest is wave-uniform base + lane*16
static __device__ __forceinline__ void gld16(const unsigned short* g,
                                             unsigned short* l) {
    __builtin_amdgcn_global_load_lds(
        (const __attribute__((address_space(1))) unsigned int*)g,
        (__attribute__((address_space(3))) unsigned int*)l, 16, 0, 0);
}

// ---------------- fused prep: x -> bf16 (blocks 0..2047) ;
//                  W [K,N] fp32 -> Wt [N,K] bf16 for 4 weights (blocks 2048..3071)
__global__ __launch_bounds__(256) void k_prep(
        const float* __restrict__ x, unsigned short* __restrict__ xb,
        const float* __restrict__ W0, const float* __restrict__ W1,
        const float* __restrict__ W2, const float* __restrict__ W3,
        unsigned short* __restrict__ T0, unsigned short* __restrict__ T1,
        unsigned short* __restrict__ T2, unsigned short* __restrict__ T3) {
    const int tid = threadIdx.x;
    if (blockIdx.x < 2048) {                       // ---- convert x -> bf16
        int i = blockIdx.x * 256 + tid;            // 8 elements/thread
        const float4* p = (const float4*)(x + (size_t)i * 8);
        float4 a = p[0], b = p[1];
        short8 o;
        o[0] = (short)f2bf(a.x); o[1] = (short)f2bf(a.y);
        o[2] = (short)f2bf(a.z); o[3] = (short)f2bf(a.w);
        o[4] = (short)f2bf(b.x); o[5] = (short)f2bf(b.y);
        o[6] = (short)f2bf(b.z); o[7] = (short)f2bf(b.w);
        ((short8*)xb)[i] = o;
        return;
    }
    // ---- transpose+convert weights
    const int t = blockIdx.x - 2048;               // 1024 blocks: z*256 + y*16 + x
    const int z = t >> 8, by = (t >> 4) & 15, bx = t & 15;
    const float* W = (z == 0) ? W0 : (z == 1) ? W1 : (z == 2) ? W2 : W3;
    unsigned short* Wt = (z == 0) ? T0 : (z == 1) ? T1 : (z == 2) ? T2 : T3;
    __shared__ float tw[64][68];
    const int k0 = bx * 64, n0 = by * 64;
#pragma unroll
    for (int r = 0; r < 4; ++r) {
        int i = tid + r * 256;
        int row = i >> 4, c4 = (i & 15) * 4;
        float4 v = *(const float4*)(W + (size_t)(k0 + row) * 1024 + n0 + c4);
        *(float4*)(&tw[row][c4]) = v;
    }
    __syncthreads();
#pragma unroll
    for (int r = 0; r < 2; ++r) {
        int i = tid + r * 256;
        int nrow = i >> 3, kc = (i & 7) * 8;
        short8 o;
#pragma unroll
        for (int j = 0; j < 8; ++j) o[j] = (short)f2bf(tw[kc + j][nrow]);
        *(short8*)(Wt + (size_t)(n0 + nrow) * 1024 + k0 + kc) = o;
    }
}

// ------------------------ GEMM, 128x64 tile, BK=64 (two k-half sub-tiles)
// C[M=4096, N] = A[M,1024](bf16) @ Bt[N,1024]^T + bias ; 16 K-iters.
// 4 waves as 2x2 -> each wave 64x32 out (acc 4x2, 16 MFMA/iter).
// MODE 0 (QKV, N=3072, grid 32x48): n0<1024 -> Qb (PRE-SCALED by log2e/32) ;
// <2048 -> Kb ; else V transposed into Vt.
// MODE 1 (O, N=1024, grid 32x16): fp32 out + bias.
template <int MODE>
__global__ __launch_bounds__(256) void k_gemm2(const unsigned short* __restrict__ A,
                                               const unsigned short* __restrict__ Bt,
                                               const float* __restrict__ bq,
                                               const float* __restrict__ bk,
                                               const float* __restrict__ bv,
                                               unsigned short* __restrict__ Qb,
                                               unsigned short* __restrict__ Kb,
                                               unsigned short* __restrict__ Vt,
                                               float* __restrict__ Co) {
    __shared__ unsigned short As[2][128 * 32];     // k-half sub-tiles, 8 KB each
    __shared__ unsigned short Bs[2][64 * 32];      // 4 KB each
    const int tid = threadIdx.x;
    const int w = tid >> 6, lane = tid & 63;
    const int quad = lane >> 4, l16 = lane & 15;
    const int wm = w >> 1, wn = w & 1;             // 2x2 waves, 64x32 out each
    const int m0 = blockIdx.x * 128, n0 = blockIdx.y * 64;
    const int lrow = lane >> 2, lch = (lane & 3) * 8;

    const unsigned short* ga = A + (size_t)(m0 + w * 32 + lrow) * 1024 + lch;
    const unsigned short* gb = Bt + (size_t)(n0 + w * 16 + (lane >> 2)) * 1024 + lch;
    const int lofsA = w * 1024 + lane * 8;         // == (w*32+lrow)*32 + lch
    const int lofsB = w * 512 + lane * 8;          // == (w*16+(lane>>2))*32 + lch

    f32x4 acc[4][2];
#pragma unroll
    for (int mt = 0; mt < 4; ++mt)
#pragma unroll
        for (int nt = 0; nt < 2; ++nt) acc[mt][nt] = (f32x4){0.f, 0.f, 0.f, 0.f};

    for (int k0 = 0; k0 < 1024; k0 += 64) {
        __syncthreads();                           // done reading prev tile
        gld16(ga + k0, &As[0][lofsA]);
        gld16(ga + 16 * 1024 + k0, &As[0][lofsA + 512]);
        gld16(ga + k0 + 32, &As[1][lofsA]);
        gld16(ga + 16 * 1024 + k0 + 32, &As[1][lofsA + 512]);
        gld16(gb + k0, &Bs[0][lofsB]);
        gld16(gb + k0 + 32, &Bs[1][lofsB]);
        __syncthreads();                           // vmcnt drain -> tile ready
#pragma unroll
        for (int kk = 0; kk < 2; ++kk) {
            short8 af[4], bf[2];
#pragma unroll
            for (int mt = 0; mt < 4; ++mt)
                af[mt] = *(const short8*)(&As[kk][(wm * 64 + mt * 16 + l16) * 32 + quad * 8]);
#pragma unroll
            for (int nt = 0; nt < 2; ++nt)
                bf[nt] = *(const short8*)(&Bs[kk][(wn * 32 + nt * 16 + l16) * 32 + quad * 8]);
#pragma unroll
            for (int mt = 0; mt < 4; ++mt)
#pragma unroll
                for (int nt = 0; nt < 2; ++nt)
                    acc[mt][nt] = MFMA16(af[mt], bf[nt], acc[mt][nt]);
        }
    }

    // epilogue: C/D layout col=lane&15, row=quad*4+reg
    if (MODE == 1) {
#pragma unroll
        for (int nt = 0; nt < 2; ++nt) {
            int col = n0 + wn * 32 + nt * 16 + l16;
            float bb = bq[col];
#pragma unroll
            for (int mt = 0; mt < 4; ++mt) {
                int row = m0 + wm * 64 + mt * 16 + quad * 4;
#pragma unroll
                for (int r = 0; r < 4; ++r)
                    Co[(size_t)(row + r) * 1024 + col] = acc[mt][nt][r] + bb;
            }
        }
    } else if (n0 < 2048) {                        // Q (pre-scaled) or K: bf16
        unsigned short* C = (n0 < 1024) ? Qb : Kb;
        const float* bias = (n0 < 1024) ? bq : bk;
        // fold 1/sqrt(E) AND log2e into Q: softmax runs in exp2 domain
        const float sc = (n0 < 1024) ? 0.03125f * 1.44269504f : 1.0f;
        int cb = (n0 < 1024) ? n0 : (n0 - 1024);
#pragma unroll
        for (int nt = 0; nt < 2; ++nt) {
            int col = cb + wn * 32 + nt * 16 + l16;
            float bb = bias[col];
#pragma unroll
            for (int mt = 0; mt < 4; ++mt) {
                int row = m0 + wm * 64 + mt * 16 + quad * 4;
#pragma unroll
                for (int r = 0; r < 4; ++r)
                    C[(size_t)(row + r) * 1024 + col] = f2bf((acc[mt][nt][r] + bb) * sc);
            }
        }
    } else {                                       // V: transposed per-head store
#pragma unroll
        for (int nt = 0; nt < 2; ++nt) {
            int vcol = (n0 - 2048) + wn * 32 + nt * 16 + l16;   // h*64+d
            float bb = bv[vcol];
#pragma unroll
            for (int mt = 0; mt < 4; ++mt) {
                int row = m0 + wm * 64 + mt * 16 + quad * 4;    // b*2048+t, t%4==0
                int b = row >> 11, t = row & 2047;
                short4v o;
#pragma unroll
                for (int r = 0; r < 4; ++r) o[r] = (short)f2bf(acc[mt][nt][r] + bb);
                *(short4v*)(&Vt[((size_t)(b * 16 + (vcol >> 6)) * 64 + (vcol & 63))
                                    * 2048 + t]) = o;
            }
        }
    }
}

// ---------------------------------------------------------------- flash attention
// Per-lane softmax in EXP2 DOMAIN (Q pre-scaled by log2e/32, exp = inline-asm
// v_exp_f32), tree reductions, defer-max THR=8, SINGLE-buffer LDS K/V staging
// with early reg prefetch, mask behind uniform kt==qb branch, P-pack/O-store
// via v_cvt_pk_bf16_f32. LDS 27.6KB. grid 1024: bh=(id&7)+8*((id>>3)&3);
// qb via balanced perm.
__global__ __launch_bounds__(256) void k_attn(const unsigned short* __restrict__ Qb,
                                              const unsigned short* __restrict__ Kb,
                                              const unsigned short* __restrict__ Vt,
                                              unsigned short* __restrict__ Ob) {
    __shared__ unsigned short Ks[64][72];          // [k16][d], 144B row stride
    __shared__ unsigned short Vs[64][72];          // [d][k]
    __shared__ unsigned short Ps[4][16][72];       // per-wave P^T relayout
    const int tid = threadIdx.x;
    const int w = tid >> 6, lane = tid & 63;
    const int quad = lane >> 4, l16 = lane & 15;
    const int id = blockIdx.x;
    const int bh = (id & 7) + 8 * ((id >> 3) & 3);
    // balanced qb permutation: per-CU work equal under round-robin placement
    const int g = id >> 5, gk = g & 7, gb2 = g >> 3;
    const int qb = (gb2 == 0) ? 31 - gk : (gb2 == 1) ? 16 + gk
                   : (gb2 == 2) ? 15 - gk : gk;
    const int b = bh >> 4, h = bh & 15;
    const int qg = qb * 64 + w * 16 + l16;         // this lane's q row
    const f32x4 zero4 = {0.f, 0.f, 0.f, 0.f};

    // staging geometry: 512 b128 chunks, thread covers rows tid>>3 and 32+(tid>>3)
    const int srow = tid >> 3, sc8 = (tid & 7) * 8;
    const unsigned short* kg0 = Kb + (size_t)(b * 2048) * 1024 + h * 64 + sc8;
    const unsigned short* vg0 = Vt + (size_t)(bh * 64 + srow) * 2048 + sc8;

    // Q as B-operand (pre-scaled by log2e/32): [n=q=l16][k=d=quad*8+j]
    short8 qf[2];
    {
        const unsigned short* qp =
            Qb + (size_t)(b * 2048 + qg) * 1024 + h * 64 + quad * 8;
        qf[0] = *(const short8*)(qp);
        qf[1] = *(const short8*)(qp + 32);
    }
    float m_ = -1e30f, l_ = 0.f;                   // per lane (q), dup over quads
    f32x4 o[4];                                    // O^T: q=l16, d=dt*16+quad*4+r
#pragma unroll
    for (int dt = 0; dt < 4; ++dt) o[dt] = zero4;

    // prologue: stage tile 0
    short8 kr0, kr1, vr0, vr1;
    kr0 = *(const short8*)(kg0 + (size_t)(srow) * 1024);
    kr1 = *(const short8*)(kg0 + (size_t)(32 + srow) * 1024);
    vr0 = *(const short8*)(vg0);
    vr1 = *(const short8*)(vg0 + (size_t)32 * 2048);
    *(short8*)(&Ks[srow][sc8]) = kr0;
    *(short8*)(&Ks[32 + srow][sc8]) = kr1;
    *(short8*)(&Vs[srow][sc8]) = vr0;
    *(short8*)(&Vs[32 + srow][sc8]) = vr1;
    __syncthreads();

    for (int kt = 0; kt <= qb; ++kt) {
        const bool more = kt < qb;
        if (more) {                                // issue loads for kt+1 EARLY;
            const unsigned short* kg = kg0 + (size_t)((kt + 1) * 64) * 1024;
            kr0 = *(const short8*)(kg + (size_t)(srow) * 1024);
            kr1 = *(const short8*)(kg + (size_t)(32 + srow) * 1024);
            vr0 = *(const short8*)(vg0 + (kt + 1) * 64);
            vr1 = *(const short8*)(vg0 + (size_t)32 * 2048 + (kt + 1) * 64);
        }                                          // ...they fly during compute

        // S^T = K Q^T : A=K[m=k16=l16][d] from LDS, B=Q. C: col=q, row=k16.
        f32x4 s[4];
#pragma unroll
        for (int kkt = 0; kkt < 4; ++kkt) {
            short8 kf0 = *(const short8*)(&Ks[kkt * 16 + l16][quad * 8]);
            short8 kf1 = *(const short8*)(&Ks[kkt * 16 + l16][32 + quad * 8]);
            s[kkt] = MFMA16(kf0, qf[0], zero4);
            s[kkt] = MFMA16(kf1, qf[1], s[kkt]);
        }

        // causal mask only on the diagonal tile (wave-uniform scalar branch)
        if (kt == qb) {
#pragma unroll
            for (int kkt = 0; kkt < 4; ++kkt) {
                int kg_ = qb * 64 + kkt * 16 + quad * 4;
#pragma unroll
                for (int r = 0; r < 4; ++r)
                    if (kg_ + r > qg) s[kkt][r] = -1e30f;
            }
        }
        // per-lane online softmax in exp2 domain; tree reductions (depth 4)
        float mk[4];
#pragma unroll
        for (int kkt = 0; kkt < 4; ++kkt)
            mk[kkt] = fmaxf(fmaxf(s[kkt][0], s[kkt][1]),
                            fmaxf(s[kkt][2], s[kkt][3]));
        float mx = fmaxf(fmaxf(mk[0], mk[1]), fmaxf(mk[2], mk[3]));
        mx = fmaxf(mx, __shfl_xor(mx, 16, 64));    // reduce over quad lanes
        mx = fmaxf(mx, __shfl_xor(mx, 32, 64));
        // T13 defer-max: rescale only when any lane exceeds m_+8 (P <= 2^8)
        if (__any(mx > m_ + 8.0f)) {
            float mnew = fmaxf(m_, mx);
            float al = exp2_hw(m_ - mnew);
            l_ *= al;
#pragma unroll
            for (int dt = 0; dt < 4; ++dt)
#pragma unroll
                for (int r = 0; r < 4; ++r) o[dt][r] *= al;
            m_ = mnew;
        }
#pragma unroll
        for (int kkt = 0; kkt < 4; ++kkt)
#pragma unroll
            for (int r = 0; r < 4; ++r)
                s[kkt][r] = exp2_hw(s[kkt][r] - m_);   // 1-instr HW 2^x
        float sk[4];
#pragma unroll
        for (int kkt = 0; kkt < 4; ++kkt)
            sk[kkt] = (s[kkt][0] + s[kkt][1]) + (s[kkt][2] + s[kkt][3]);
        float sum = (sk[0] + sk[1]) + (sk[2] + sk[3]);
        sum += __shfl_xor(sum, 16, 64);
        sum += __shfl_xor(sum, 32, 64);
        l_ += sum;

        // P^T relayout via cvt_pk: 2 packed dwords per kkt -> one b64 store
#pragma unroll
        for (int kkt = 0; kkt < 4; ++kkt) {
            uint2 pk;
            pk.x = cvtpk_bf16(s[kkt][0], s[kkt][1]);
            pk.y = cvtpk_bf16(s[kkt][2], s[kkt][3]);
            *(uint2*)(&Ps[w][l16][kkt * 16 + quad * 4]) = pk;
        }
        __threadfence_block();                     // lgkmcnt drain (per-wave Ps)

        // O^T += V^T P^T : A=V^T[m=d16=l16][k] from LDS, B=P^T[n=q=l16][k]
#pragma unroll
        for (int kks = 0; kks < 2; ++kks) {
            short8 pf = *(const short8*)(&Ps[w][l16][kks * 32 + quad * 8]);
#pragma unroll
            for (int dt = 0; dt < 4; ++dt) {
                short8 vf = *(const short8*)(
                    &Vs[dt * 16 + l16][kks * 32 + quad * 8]);
                o[dt] = MFMA16(vf, pf, o[dt]);
            }
        }

        if (more) {                                // write-late: single buffer
            __syncthreads();                       // all waves done reading K/V
            *(short8*)(&Ks[srow][sc8]) = kr0;
            *(short8*)(&Ks[32 + srow][sc8]) = kr1;
            *(short8*)(&Vs[srow][sc8]) = vr0;
            *(short8*)(&Vs[32 + srow][sc8]) = vr1;
            __syncthreads();                       // tile kt+1 staged
        }
    }

    // epilogue: lane q=qg, d = dt*16+quad*4+r -> 4 consecutive d per b64 store
    float inv = 1.0f / l_;
    unsigned short* op = Ob + (size_t)(b * 2048 + qg) * 1024 + h * 64 + quad * 4;
#pragma unroll
    for (int dt = 0; dt < 4; ++dt) {
        uint2 ov;
        ov.x = cvtpk_bf16(o[dt][0] * inv, o[dt][1] * inv);
        ov.y = cvtpk_bf16(o[dt][2] * inv, o[dt][3] * inv);
        *(uint2*)(op + dt * 16) = ov;
    }
}

// ---------------------------------------------------------------- launch
extern "C" void kernel_launch(void* const* d_in, const int* in_sizes, int n_in,
                              void* d_out, int out_size, void* d_ws, size_t ws_size,
                              hipStream_t stream) {
    const float* x  = (const float*)d_in[0];
    const float* Wq = (const float*)d_in[1];
    const float* bq = (const float*)d_in[2];
    const float* Wk = (const float*)d_in[3];
    const float* bk = (const float*)d_in[4];
    const float* Wv = (const float*)d_in[5];
    const float* bv = (const float*)d_in[6];
    const float* Wo = (const float*)d_in[7];
    const float* bo = (const float*)d_in[8];
    float* out = (float*)d_out;                    // fp32 output

    const size_t M4 = 4194304, M1 = 1048576;
    const size_t NEED = (M4 + M4 + 3 * M1 + M1) * 2;   // 24 MB
    if (ws_size < NEED) return;
    unsigned short* ws = (unsigned short*)d_ws;
    unsigned short* xb  = ws;                      // 8 MB (dead after QKV gemm)
    unsigned short* Ob  = ws;                      //   ... then Ob (attn output)
    unsigned short* Vt  = ws + M4;                 // 8 MB, [(b*16+h)*64+d][t]
    unsigned short* WtQ = ws + 2 * M4;             // 6 MB: Wq^T,Wk^T,Wv^T stacked
    unsigned short* Wto = WtQ + 3 * M1;            // 2 MB: Wo^T
    unsigned short* Qb  = (unsigned short*)d_out;  // 8 MB scratch in d_out
    unsigned short* Kb  = Qb + M4;                 // 8 MB scratch in d_out

    k_prep<<<3072, 256, 0, stream>>>(x, xb, Wq, Wk, Wv, Wo,
                                     WtQ, WtQ + M1, WtQ + 2 * M1, Wto);
    k_gemm2<0><<<dim3(32, 48), 256, 0, stream>>>(xb, WtQ, bq, bk, bv,
                                                 Qb, Kb, Vt, nullptr);
    k_attn<<<1024, 256, 0, stream>>>(Qb, Kb, Vt, Ob);
    k_gemm2<1><<<dim3(32, 16), 256, 0, stream>>>(Ob, Wto, bo, nullptr, nullptr,
                                                 nullptr, nullptr, nullptr, out);
}